// Round 8
// baseline (284.030 us; speedup 1.0000x reference)
//
#include <hip/hip_runtime.h>
#include <hip/hip_cooperative_groups.h>

namespace cg = cooperative_groups;

// N=2, L=1024, C=256, H=64, E=16, CL=64, LOUT=960
// qT/kT: [n][h][l][e] fp32 ; vT: [n][h][l] fp32 ; attT: [n][h][l'] fp32

typedef __attribute__((ext_vector_type(8))) __bf16 bf16x8;
typedef __attribute__((ext_vector_type(8))) short short8;
typedef __attribute__((ext_vector_type(4))) float f32x4;

__device__ inline unsigned short bf16_rne(float x) {
    unsigned u = __builtin_bit_cast(unsigned, x);
    unsigned r = u + 0x7fffu + ((u >> 16) & 1u);
    return (unsigned short)(r >> 16);
}
__device__ inline float bf16_f(unsigned short h) {
    return __builtin_bit_cast(float, (unsigned)h << 16);
}

__device__ __forceinline__ bf16x8 ldsfrag(const unsigned short* lds, int t, int row, int so) {
    return __builtin_bit_cast(bf16x8, *reinterpret_cast<const short8*>(
        lds + t * 8192 + row * 64 + (((so ^ (row & 7)) & 7) << 3)));
}

// ---------------------------------------------------------------------------
// ONE cooperative kernel, 4 phases with grid.sync() between.
// Grid 256 x 512 (1 block/CU, 64KB LDS union -> co-resident).
// Phase 0: bf16 hi/lo split of X and [Wq;Wk;Wv]  (grid-stride)
// Phase 1: QKV projection, MFMA split-3; 272 jobs (16m x 17o), 16 blocks x2
// Phase 2: sliding-window attention; 512 jobs = 2 per block (256-thr halves)
// Phase 3: 4x FC + head; 120 jobs on blocks 0..119
// ---------------------------------------------------------------------------
__global__ __launch_bounds__(512, 2) void fused_all(
    const float* __restrict__ X,
    const float* __restrict__ Wq, const float* __restrict__ bq,
    const float* __restrict__ Wk, const float* __restrict__ bk,
    const float* __restrict__ Wv, const float* __restrict__ bv,
    const float* __restrict__ PE,
    const float* __restrict__ fc_w, const float* __restrict__ fc_b,
    const float* __restrict__ Wout, const float* __restrict__ bout,
    float* __restrict__ out,
    float* __restrict__ qT, float* __restrict__ kT, float* __restrict__ vT,
    float* __restrict__ attT,
    unsigned short* __restrict__ XhG, unsigned short* __restrict__ XlG,
    unsigned short* __restrict__ WhG, unsigned short* __restrict__ WlG)
{
    __shared__ __align__(16) char smem[65536];
    cg::grid_group grid = cg::this_grid();

    const int tid = threadIdx.x;
    const int bid = blockIdx.x;

    // ================= phase 0: convert/split =================
    {
        const int NX = 131072;   // 2048*256/4
        const int NW = 135168;   // 2112*256/4
        for (int g = bid * 512 + tid; g < NX + NW; g += 256 * 512) {
            float4 v;
            unsigned short *dh, *dl;
            int off;
            if (g < NX) {
                off = g * 4;
                v = *reinterpret_cast<const float4*>(&X[off]);
                dh = XhG; dl = XlG;
            } else {
                off = (g - NX) * 4;
                const int row = off >> 8, col = off & 255;
                const float* s;
                if (row < 1024)      s = &Wq[row * 256 + col];
                else if (row < 2048) s = &Wk[(row - 1024) * 256 + col];
                else                 s = &Wv[(row - 2048) * 256 + col];
                v = *reinterpret_cast<const float4*>(s);
                dh = WhG; dl = WlG;
            }
            unsigned short h0 = bf16_rne(v.x), h1 = bf16_rne(v.y), h2 = bf16_rne(v.z), h3 = bf16_rne(v.w);
            unsigned short l0 = bf16_rne(v.x - bf16_f(h0));
            unsigned short l1 = bf16_rne(v.y - bf16_f(h1));
            unsigned short l2 = bf16_rne(v.z - bf16_f(h2));
            unsigned short l3 = bf16_rne(v.w - bf16_f(h3));
            *reinterpret_cast<ushort4*>(&dh[off]) = make_ushort4(h0, h1, h2, h3);
            *reinterpret_cast<ushort4*>(&dl[off]) = make_ushort4(l0, l1, l2, l3);
        }
    }
    __threadfence();
    grid.sync();

    // ================= phase 1: QKV MFMA =================
    {
        unsigned short* lds = (unsigned short*)smem;   // 4 tiles x 128 x 64
        const int lane = tid & 63;
        const int wid  = tid >> 6;
        const int wm   = wid >> 2;
        const int wn   = wid & 3;
        const int r8 = lane >> 3;
        const int ss = (lane & 7) ^ r8;

        for (int job = bid; job < 272; job += 256) {
            const int m0 = (job & 15) * 128;
            const int o0 = (job >> 4) * 128;

            f32x4 acc[4][2];
            #pragma unroll
            for (int i = 0; i < 4; ++i)
                #pragma unroll
                for (int j = 0; j < 2; ++j)
                    acc[i][j] = f32x4{0.f, 0.f, 0.f, 0.f};

            for (int k0 = 0; k0 < 256; k0 += 64) {
                #pragma unroll
                for (int j = 0; j < 8; ++j) {
                    const int c   = (wid << 3) | j;
                    const int t   = c >> 4;
                    const int rg  = c & 15;
                    const int row = (rg << 3) + r8;
                    const unsigned short* gsrc;
                    if (t == 0)      gsrc = &XhG[(m0 + row) * 256 + k0 + (ss << 3)];
                    else if (t == 1) gsrc = &XlG[(m0 + row) * 256 + k0 + (ss << 3)];
                    else if (t == 2) gsrc = &WhG[(o0 + row) * 256 + k0 + (ss << 3)];
                    else             gsrc = &WlG[(o0 + row) * 256 + k0 + (ss << 3)];
                    char* lbase = (char*)lds + (c << 10);
                    __builtin_amdgcn_global_load_lds(
                        (const __attribute__((address_space(1))) void*)gsrc,
                        (__attribute__((address_space(3))) void*)lbase, 16, 0, 0);
                }
                __syncthreads();

                #pragma unroll
                for (int kk = 0; kk < 64; kk += 32) {
                    const int so = (kk >> 3) + (lane >> 4);
                    bf16x8 aH[4], aL[4], bH[2], bL[2];
                    #pragma unroll
                    for (int mt = 0; mt < 4; ++mt) {
                        const int ar = wm * 64 + mt * 16 + (lane & 15);
                        aH[mt] = ldsfrag(lds, 0, ar, so);
                        aL[mt] = ldsfrag(lds, 1, ar, so);
                    }
                    #pragma unroll
                    for (int ot = 0; ot < 2; ++ot) {
                        const int br = wn * 32 + ot * 16 + (lane & 15);
                        bH[ot] = ldsfrag(lds, 2, br, so);
                        bL[ot] = ldsfrag(lds, 3, br, so);
                    }
                    #pragma unroll
                    for (int mt = 0; mt < 4; ++mt)
                        #pragma unroll
                        for (int ot = 0; ot < 2; ++ot) {
                            acc[mt][ot] = __builtin_amdgcn_mfma_f32_16x16x32_bf16(aH[mt], bH[ot], acc[mt][ot], 0, 0, 0);
                            acc[mt][ot] = __builtin_amdgcn_mfma_f32_16x16x32_bf16(aH[mt], bL[ot], acc[mt][ot], 0, 0, 0);
                            acc[mt][ot] = __builtin_amdgcn_mfma_f32_16x16x32_bf16(aL[mt], bH[ot], acc[mt][ot], 0, 0, 0);
                        }
                }
                __syncthreads();
            }

            const int drow = (lane >> 4) * 4;
            const int dcol = lane & 15;
            const int mode = (o0 < 1024) ? 0 : (o0 < 2048 ? 1 : 2);

            if (mode < 2) {
                float* __restrict__ T = mode ? kT : qT;
                const float* __restrict__ bias = mode ? bk : bq;
                const int ob = mode * 1024;
                #pragma unroll
                for (int ot = 0; ot < 2; ++ot) {
                    const int o = o0 + wn * 32 + ot * 16 + dcol;
                    const int h = (o >> 4) & 63;
                    const int e = o & 15;
                    const float bval = bias[o - ob];
                    #pragma unroll
                    for (int mt = 0; mt < 4; ++mt)
                        #pragma unroll
                        for (int r = 0; r < 4; ++r) {
                            const int m = m0 + wm * 64 + mt * 16 + drow + r;
                            const int n = m >> 10, l = m & 1023;
                            T[((n * 64 + h) * 1024 + l) * 16 + e] = acc[mt][ot][r] + bval;
                        }
                }
            } else if (wn < 2) {
                #pragma unroll
                for (int ot = 0; ot < 2; ++ot) {
                    const int hV = wn * 32 + ot * 16 + dcol;
                    const float bval = bv[hV];
                    #pragma unroll
                    for (int mt = 0; mt < 4; ++mt)
                        #pragma unroll
                        for (int r = 0; r < 4; ++r) {
                            const int m = m0 + wm * 64 + mt * 16 + drow + r;
                            const int n = m >> 10, l = m & 1023;
                            vT[(n * 64 + hV) * 1024 + l] = acc[mt][ot][r] + bval;
                        }
                }
            }
        }
    }
    __threadfence();
    grid.sync();

    // ================= phase 2: attention (2 jobs/block) =================
    {
        char* base = smem + (tid >> 8) * 32768;
        float2* kc     = (float2*)base;            // 8 planes x 322 -> 20608 B
        float*  pe_lds = (float*)(base + 20608);   // 64x16 -> 4096 B
        float*  v_lds  = (float*)(base + 24704);   // 320   -> 1280 B

        const int subtid = tid & 255;
        const int lane = subtid & 63;
        const int w    = subtid >> 6;
        const int job = bid * 2 + (tid >> 8);      // 0..511
        const int xb = job & 3;
        const int h  = (job >> 2) & 63;
        const int n  = job >> 8;
        const int l0 = xb * 256;

        const int nrows = min(319, 1024 - l0);
        const float4* kb4 = reinterpret_cast<const float4*>(kT + ((size_t)(n * 64 + h) * 1024 + l0) * 16);
        for (int u = subtid; u < nrows * 4; u += 256) {
            const int row = u >> 2, f = u & 3;
            const float4 g = kb4[u];
            kc[(2 * f + 0) * 322 + row] = make_float2(g.x, g.y);
            kc[(2 * f + 1) * 322 + row] = make_float2(g.z, g.w);
        }
        {
            const int d = subtid >> 2, f = subtid & 3;
            *reinterpret_cast<float4*>(&pe_lds[d * 16 + f * 4]) =
                *reinterpret_cast<const float4*>(&PE[(d * 64 + h) * 16 + f * 4]);
        }
        const float* vbase = vT + (size_t)(n * 64 + h) * 1024 + l0;
        for (int u = subtid; u < nrows; u += 256) v_lds[u] = vbase[u];

        const int lout = l0 + w * 64 + lane;
        const bool active = lout < 960;
        const int lq = active ? lout : 959;
        float4 q0, q1, q2, q3;
        {
            const float4* qb = reinterpret_cast<const float4*>(
                qT + ((size_t)(n * 64 + h) * 1024 + lq + 32) * 16);
            q0 = qb[0]; q1 = qb[1]; q2 = qb[2]; q3 = qb[3];
        }
        __syncthreads();   // both halves execute uniformly

        const int rbase = w * 64 + lane;
        float den = 0.f, pv = 0.f;
        #pragma unroll 2
        for (int d = 0; d < 64; ++d) {
            const int r = rbase + d;
            const float2 c0 = kc[0 * 322 + r], c1 = kc[1 * 322 + r];
            const float2 c2 = kc[2 * 322 + r], c3 = kc[3 * 322 + r];
            const float2 c4 = kc[4 * 322 + r], c5 = kc[5 * 322 + r];
            const float2 c6 = kc[6 * 322 + r], c7 = kc[7 * 322 + r];
            const float4* pr = reinterpret_cast<const float4*>(&pe_lds[d * 16]);
            const float4 p0 = pr[0], p1 = pr[1], p2 = pr[2], p3 = pr[3];
            float s0 = (c0.x + p0.x) * q0.x + (c0.y + p0.y) * q0.y
                     + (c1.x + p0.z) * q0.z + (c1.y + p0.w) * q0.w;
            float s1 = (c2.x + p1.x) * q1.x + (c2.y + p1.y) * q1.y
                     + (c3.x + p1.z) * q1.z + (c3.y + p1.w) * q1.w;
            float s2 = (c4.x + p2.x) * q2.x + (c4.y + p2.y) * q2.y
                     + (c5.x + p2.z) * q2.z + (c5.y + p2.w) * q2.w;
            float s3 = (c6.x + p3.x) * q3.x + (c6.y + p3.y) * q3.y
                     + (c7.x + p3.z) * q3.z + (c7.y + p3.w) * q3.w;
            const float s = (s0 + s1) + (s2 + s3);
            const float p = __expf(s - 16.f);   // fixed shift: exact softmax ratio
            den += p;
            pv += p * v_lds[r];
        }
        if (active)
            attT[(size_t)(n * 64 + h) * 960 + lout] = fmaxf(pv / den, 0.f);
    }
    __threadfence();
    grid.sync();

    // ================= phase 3: FC stack (blocks 0..119) =================
    if (bid < 120) {
        float* w_lds  = (float*)smem;               // 64*68 -> 17408 B
        float* wo_lds = (float*)(smem + 17408);     // 192   -> 768 B
        float* bufA   = (float*)(smem + 18176);     // 16*68 -> 4352 B
        float* bufB   = (float*)(smem + 22528);     // 16*68 -> 4352 B

        const int o  = tid & 63;
        const int rr = tid >> 6;           // 0..7
        const int n  = bid / 60;
        const int l0 = (bid - n * 60) * 16;
        const int R0 = n * 960 + l0;

        for (int idx = tid; idx < 192; idx += 512) wo_lds[idx] = Wout[idx];
        for (int idx = tid; idx < 1024; idx += 512) {
            const int hh = idx >> 4, r = idx & 15;
            bufA[r * 68 + hh] = attT[(size_t)(n * 64 + hh) * 960 + l0 + r];
        }

        float* cur = bufA;
        float* nxt = bufB;

        for (int layer = 0; layer < 4; ++layer) {
            __syncthreads();
            const float4* wsrc = reinterpret_cast<const float4*>(fc_w + layer * 4096);
            for (int u = tid; u < 1024; u += 512) {
                const int oo = u >> 4, f = u & 15;
                *reinterpret_cast<float4*>(&w_lds[oo * 68 + f * 4]) = wsrc[u];
            }
            __syncthreads();
            const float bias = fc_b[layer * 64 + o];
            const float4* wr = reinterpret_cast<const float4*>(&w_lds[o * 68]);
            #pragma unroll
            for (int rb = 0; rb < 2; ++rb) {
                const int r = rr + rb * 8;
                float acc = bias;
                const float4* cr = reinterpret_cast<const float4*>(&cur[r * 68]);
                #pragma unroll
                for (int t = 0; t < 16; ++t) {
                    const float4 c = cr[t], wv = wr[t];
                    acc += c.x * wv.x + c.y * wv.y + c.z * wv.z + c.w * wv.w;
                }
                nxt[r * 68 + o] = fmaxf(acc, 0.f);
            }
            float* tmp = cur; cur = nxt; nxt = tmp;
        }
        __syncthreads();

        if (o < 3) {
            #pragma unroll
            for (int rb = 0; rb < 2; ++rb) {
                const int r = rr + rb * 8;
                float acc = bout[o];
                #pragma unroll
                for (int hh = 0; hh < 64; ++hh)
                    acc += cur[r * 68 + hh] * wo_lds[o * 64 + hh];
                out[(R0 + r) * 3 + o] = acc;
            }
        }
    }
}

// ---------------------------------------------------------------------------
extern "C" void kernel_launch(void* const* d_in, const int* in_sizes, int n_in,
                              void* d_out, int out_size, void* d_ws, size_t ws_size,
                              hipStream_t stream) {
    const float* x    = (const float*)d_in[0];
    const float* Wq   = (const float*)d_in[1];
    const float* bq   = (const float*)d_in[2];
    const float* Wk   = (const float*)d_in[3];
    const float* bk   = (const float*)d_in[4];
    const float* Wv   = (const float*)d_in[5];
    const float* bv   = (const float*)d_in[6];
    const float* PE   = (const float*)d_in[7];
    const float* fc_w = (const float*)d_in[8];
    const float* fc_b = (const float*)d_in[9];
    const float* Wout = (const float*)d_in[10];
    const float* bout = (const float*)d_in[11];
    float* out = (float*)d_out;

    float* ws = (float*)d_ws;
    float* qT   = ws;                      // 2,097,152 f
    float* kT   = qT + 2097152;            // 2,097,152 f
    float* vT   = kT + 2097152;            // 131,072 f
    float* attT = vT + 131072;             // 122,880 f
    unsigned short* XhG = (unsigned short*)(attT + 122880);
    unsigned short* XlG = XhG + 524288;
    unsigned short* WhG = XlG + 524288;
    unsigned short* WlG = WhG + 540672;

    void* args[] = {
        (void*)&x, (void*)&Wq, (void*)&bq, (void*)&Wk, (void*)&bk,
        (void*)&Wv, (void*)&bv, (void*)&PE, (void*)&fc_w, (void*)&fc_b,
        (void*)&Wout, (void*)&bout, (void*)&out,
        (void*)&qT, (void*)&kT, (void*)&vT, (void*)&attT,
        (void*)&XhG, (void*)&XlG, (void*)&WhG, (void*)&WlG };

    hipLaunchCooperativeKernel((void*)fused_all, dim3(256), dim3(512),
                               args, 0, stream);
}

// Round 10
// 52.992 us; speedup vs baseline: 5.3599x; 5.3599x over previous
//
#include <hip/hip_runtime.h>

// N=2, L=1024, C=256, H=64, E=16, CL=64, LOUT=960
// qT/kT: [n][h][l][e] fp32 ; vT: [n][h][l] fp32 ; attT: [n][h][l'] fp32

typedef __attribute__((ext_vector_type(8))) __bf16 bf16x8;
typedef __attribute__((ext_vector_type(8))) short short8;
typedef __attribute__((ext_vector_type(4))) float f32x4;

__device__ inline unsigned short bf16_rne(float x) {
    unsigned u = __builtin_bit_cast(unsigned, x);
    unsigned r = u + 0x7fffu + ((u >> 16) & 1u);
    return (unsigned short)(r >> 16);
}
__device__ inline float bf16_f(unsigned short h) {
    return __builtin_bit_cast(float, (unsigned)h << 16);
}

// ---------------------------------------------------------------------------
// Kernel 0: split X and W=[Wq;Wk;Wv] into bf16 hi/lo planes.
// ---------------------------------------------------------------------------
__global__ __launch_bounds__(256) void convert_split(
    const float* __restrict__ X,
    const float* __restrict__ Wq, const float* __restrict__ Wk, const float* __restrict__ Wv,
    unsigned short* __restrict__ XhG, unsigned short* __restrict__ XlG,
    unsigned short* __restrict__ WhG, unsigned short* __restrict__ WlG)
{
    const int g = blockIdx.x * 256 + threadIdx.x;
    const int NX = 131072;
    const int NW = 135168;
    if (g >= NX + NW) return;

    float4 v;
    unsigned short *dh, *dl;
    int off;
    if (g < NX) {
        off = g * 4;
        v = *reinterpret_cast<const float4*>(&X[off]);
        dh = XhG; dl = XlG;
    } else {
        off = (g - NX) * 4;
        const int row = off >> 8, col = off & 255;
        const float* s;
        if (row < 1024)      s = &Wq[row * 256 + col];
        else if (row < 2048) s = &Wk[(row - 1024) * 256 + col];
        else                 s = &Wv[(row - 2048) * 256 + col];
        v = *reinterpret_cast<const float4*>(s);
        dh = WhG; dl = WlG;
    }
    unsigned short h0 = bf16_rne(v.x), h1 = bf16_rne(v.y), h2 = bf16_rne(v.z), h3 = bf16_rne(v.w);
    unsigned short l0 = bf16_rne(v.x - bf16_f(h0));
    unsigned short l1 = bf16_rne(v.y - bf16_f(h1));
    unsigned short l2 = bf16_rne(v.z - bf16_f(h2));
    unsigned short l3 = bf16_rne(v.w - bf16_f(h3));
    ushort4 hv = make_ushort4(h0, h1, h2, h3);
    ushort4 lv = make_ushort4(l0, l1, l2, l3);
    *reinterpret_cast<ushort4*>(&dh[off]) = hv;
    *reinterpret_cast<ushort4*>(&dl[off]) = lv;
}

// ---------------------------------------------------------------------------
// Kernel 1 (v3.1): QKV projection via MFMA, bf16 split-3 (XhWh + XhWl + XlWh).
// BM=64, BN=128, BK=64. 256 thr (4 waves 2m x 2n, wave tile 32x64).
// 544 jobs = 2.125/CU. LDS 48KB -> 3 blocks/CU.
// Chunk c staged at LDS byte c*1024 (linear gload_lds dest); pre-swizzled
// global source ss=(lane&7)^(lane>>3); XOR-swz read (rule 21).
// LDS map (ushort units): Xh @0 (chunks 0-7), Xl @4096 (8-15),
//                         Wh @8192 (16-31), Wl @16384 (32-47).
// [R9 bug: bL read base was 20480 (byte/ushort confusion) -> Wl term garbage]
// ---------------------------------------------------------------------------
__device__ __forceinline__ bf16x8 ldsfrag2(const unsigned short* lds, int base, int row, int so) {
    return __builtin_bit_cast(bf16x8, *reinterpret_cast<const short8*>(
        lds + base + row * 64 + (((so ^ (row & 7)) & 7) << 3)));
}

__global__ __launch_bounds__(256, 3) void qkv_mfma(
    const unsigned short* __restrict__ XhG, const unsigned short* __restrict__ XlG,
    const unsigned short* __restrict__ WhG, const unsigned short* __restrict__ WlG,
    const float* __restrict__ bq, const float* __restrict__ bk, const float* __restrict__ bv,
    float* __restrict__ qT, float* __restrict__ kT, float* __restrict__ vT)
{
    __shared__ unsigned short lds[24576];   // 48 KB

    const int tid  = threadIdx.x;
    const int lane = tid & 63;
    const int wid  = tid >> 6;          // 0..3
    const int wm   = wid >> 1;          // 0..1 -> m half (32 rows)
    const int wn   = wid & 1;           // 0..1 -> n half (64 cols)

    const int job = blockIdx.x;
    int m0, o0;
    if (job < 512) { m0 = (job & 31) * 64; o0 = (job >> 5) * 128; }
    else           { m0 = (job - 512) * 64; o0 = 2048; }

    f32x4 acc[2][4];
    #pragma unroll
    for (int i = 0; i < 2; ++i)
        #pragma unroll
        for (int j = 0; j < 4; ++j)
            acc[i][j] = f32x4{0.f, 0.f, 0.f, 0.f};

    const int r8 = lane >> 3;           // row within 8-row chunk
    const int ss = (lane & 7) ^ r8;     // pre-swizzled source slot

    for (int k0 = 0; k0 < 256; k0 += 64) {
        // ---- stage 48 chunks (12 per wave) via global_load_lds width 16
        #pragma unroll
        for (int j = 0; j < 12; ++j) {
            const int c = wid * 12 + j;   // 0..47 (wave-uniform)
            const unsigned short* gsrc;
            if (c < 8)       gsrc = &XhG[(m0 + (c << 3) + r8) * 256 + k0 + (ss << 3)];
            else if (c < 16) gsrc = &XlG[(m0 + ((c - 8) << 3) + r8) * 256 + k0 + (ss << 3)];
            else if (c < 32) gsrc = &WhG[(o0 + ((c - 16) << 3) + r8) * 256 + k0 + (ss << 3)];
            else             gsrc = &WlG[(o0 + ((c - 32) << 3) + r8) * 256 + k0 + (ss << 3)];
            char* lbase = (char*)lds + (c << 10);   // uniform; HW adds lane*16
            __builtin_amdgcn_global_load_lds(
                (const __attribute__((address_space(1))) void*)gsrc,
                (__attribute__((address_space(3))) void*)lbase, 16, 0, 0);
        }
        __syncthreads();   // drains vmcnt before barrier

        // ---- compute: 48 MFMA per k0 per wave
        #pragma unroll
        for (int kk = 0; kk < 64; kk += 32) {
            const int so = (kk >> 3) + (lane >> 4);   // 16B slot 0..7
            bf16x8 aH[2], aL[2], bH[4], bL[4];
            #pragma unroll
            for (int mt = 0; mt < 2; ++mt) {
                const int ar = wm * 32 + mt * 16 + (lane & 15);
                aH[mt] = ldsfrag2(lds, 0, ar, so);
                aL[mt] = ldsfrag2(lds, 4096, ar, so);
            }
            #pragma unroll
            for (int ot = 0; ot < 4; ++ot) {
                const int br = wn * 64 + ot * 16 + (lane & 15);
                bH[ot] = ldsfrag2(lds, 8192, br, so);
                bL[ot] = ldsfrag2(lds, 16384, br, so);   // FIXED: was 20480
            }
            #pragma unroll
            for (int mt = 0; mt < 2; ++mt)
                #pragma unroll
                for (int ot = 0; ot < 4; ++ot) {
                    acc[mt][ot] = __builtin_amdgcn_mfma_f32_16x16x32_bf16(aH[mt], bH[ot], acc[mt][ot], 0, 0, 0);
                    acc[mt][ot] = __builtin_amdgcn_mfma_f32_16x16x32_bf16(aH[mt], bL[ot], acc[mt][ot], 0, 0, 0);
                    acc[mt][ot] = __builtin_amdgcn_mfma_f32_16x16x32_bf16(aL[mt], bH[ot], acc[mt][ot], 0, 0, 0);
                }
        }
        __syncthreads();   // protect LDS before next stage
    }

    // ---- epilogue: bias + transposed scatter
    const int drow = (lane >> 4) * 4;
    const int dcol = lane & 15;
    const int mode = (o0 < 1024) ? 0 : (o0 < 2048 ? 1 : 2);

    if (mode < 2) {
        float* __restrict__ T = mode ? kT : qT;
        const float* __restrict__ bias = mode ? bk : bq;
        const int ob = mode * 1024;
        #pragma unroll
        for (int ot = 0; ot < 4; ++ot) {
            const int o = o0 + wn * 64 + ot * 16 + dcol;
            const int h = (o >> 4) & 63;
            const int e = o & 15;
            const float bval = bias[o - ob];
            #pragma unroll
            for (int mt = 0; mt < 2; ++mt)
                #pragma unroll
                for (int r = 0; r < 4; ++r) {
                    const int m = m0 + wm * 32 + mt * 16 + drow + r;
                    const int n = m >> 10, l = m & 1023;
                    T[((n * 64 + h) * 1024 + l) * 16 + e] = acc[mt][ot][r] + bval;
                }
        }
    } else if (wn == 0) {   // V: cols 2048..2111 only (first 64 of tile)
        #pragma unroll
        for (int ot = 0; ot < 4; ++ot) {
            const int hV = ot * 16 + dcol;   // 0..63
            const float bval = bv[hV];
            #pragma unroll
            for (int mt = 0; mt < 2; ++mt)
                #pragma unroll
                for (int r = 0; r < 4; ++r) {
                    const int m = m0 + wm * 32 + mt * 16 + drow + r;
                    const int n = m >> 10, l = m & 1023;
                    vT[(n * 64 + hV) * 1024 + l] = acc[mt][ot][r] + bval;
                }
        }
    }
}

// ---------------------------------------------------------------------------
// Kernel 2 (v4): sliding-window attention. 256 thr (4 waves), block handles
// (n, h, 256 consecutive outputs). Lane = output position.
// K column-major float2 e-pair planes, stride 322 (2-way alias only).
// ---------------------------------------------------------------------------
__global__ __launch_bounds__(256) void attn_kernel(
    const float* __restrict__ qT, const float* __restrict__ kT,
    const float* __restrict__ vT, const float* __restrict__ PE,
    float* __restrict__ attT)
{
    __shared__ float2 kc[8 * 322];
    __shared__ float pe_lds[64 * 16];
    __shared__ float v_lds[320];

    const int tid  = threadIdx.x;
    const int lane = tid & 63;
    const int w    = tid >> 6;
    const int xb = blockIdx.x;
    const int h  = blockIdx.y;
    const int n  = blockIdx.z;
    const int l0 = xb * 256;

    const int nrows = min(319, 1024 - l0);
    const float4* kb4 = reinterpret_cast<const float4*>(kT + ((size_t)(n * 64 + h) * 1024 + l0) * 16);
    for (int u = tid; u < nrows * 4; u += 256) {
        const int row = u >> 2, f = u & 3;
        const float4 g = kb4[u];
        kc[(2 * f + 0) * 322 + row] = make_float2(g.x, g.y);
        kc[(2 * f + 1) * 322 + row] = make_float2(g.z, g.w);
    }
    {
        const int d = tid >> 2, f = tid & 3;
        *reinterpret_cast<float4*>(&pe_lds[d * 16 + f * 4]) =
            *reinterpret_cast<const float4*>(&PE[(d * 64 + h) * 16 + f * 4]);
    }
    const float* vbase = vT + (size_t)(n * 64 + h) * 1024 + l0;
    for (int u = tid; u < nrows; u += 256) v_lds[u] = vbase[u];

    const int lout = l0 + w * 64 + lane;
    const bool active = lout < 960;
    const int lq = active ? lout : 959;
    float4 q0, q1, q2, q3;
    {
        const float4* qb = reinterpret_cast<const float4*>(
            qT + ((size_t)(n * 64 + h) * 1024 + lq + 32) * 16);
        q0 = qb[0]; q1 = qb[1]; q2 = qb[2]; q3 = qb[3];
    }
    __syncthreads();

    const int rbase = w * 64 + lane;
    float den = 0.f, pv = 0.f;
    #pragma unroll 2
    for (int d = 0; d < 64; ++d) {
        const int r = rbase + d;
        const float2 c0 = kc[0 * 322 + r], c1 = kc[1 * 322 + r];
        const float2 c2 = kc[2 * 322 + r], c3 = kc[3 * 322 + r];
        const float2 c4 = kc[4 * 322 + r], c5 = kc[5 * 322 + r];
        const float2 c6 = kc[6 * 322 + r], c7 = kc[7 * 322 + r];
        const float4* pr = reinterpret_cast<const float4*>(&pe_lds[d * 16]);
        const float4 p0 = pr[0], p1 = pr[1], p2 = pr[2], p3 = pr[3];
        float s0 = (c0.x + p0.x) * q0.x + (c0.y + p0.y) * q0.y
                 + (c1.x + p0.z) * q0.z + (c1.y + p0.w) * q0.w;
        float s1 = (c2.x + p1.x) * q1.x + (c2.y + p1.y) * q1.y
                 + (c3.x + p1.z) * q1.z + (c3.y + p1.w) * q1.w;
        float s2 = (c4.x + p2.x) * q2.x + (c4.y + p2.y) * q2.y
                 + (c5.x + p2.z) * q2.z + (c5.y + p2.w) * q2.w;
        float s3 = (c6.x + p3.x) * q3.x + (c6.y + p3.y) * q3.y
                 + (c7.x + p3.z) * q3.z + (c7.y + p3.w) * q3.w;
        const float s = (s0 + s1) + (s2 + s3);
        const float p = __expf(s - 16.f);   // fixed shift: exact softmax ratio
        den += p;
        pv += p * v_lds[r];
    }
    if (active)
        attT[(size_t)(n * 64 + h) * 960 + lout] = fmaxf(pv / den, 0.f);
}

// ---------------------------------------------------------------------------
// Kernel 3 (v3): 4x FC(64->64, ReLU) + head. 512 thr, 16 rows/block, 120 blk.
// ---------------------------------------------------------------------------
__global__ __launch_bounds__(512) void fc_kernel(
    const float* __restrict__ attT,
    const float* __restrict__ fc_w, const float* __restrict__ fc_b,
    const float* __restrict__ Wout, const float* __restrict__ bout,
    float* __restrict__ out)
{
    __shared__ float w_lds[64 * 68];
    __shared__ float wo_lds[3 * 64];
    __shared__ float bufA[16 * 68];
    __shared__ float bufB[16 * 68];

    const int tid = threadIdx.x;
    const int o  = tid & 63;
    const int rr = tid >> 6;
    const int blk = blockIdx.x;
    const int n  = blk / 60;
    const int l0 = (blk - n * 60) * 16;
    const int R0 = n * 960 + l0;

    for (int idx = tid; idx < 192; idx += 512) wo_lds[idx] = Wout[idx];
    for (int idx = tid; idx < 1024; idx += 512) {
        const int hh = idx >> 4, r = idx & 15;
        bufA[r * 68 + hh] = attT[(size_t)(n * 64 + hh) * 960 + l0 + r];
    }

    float* cur = bufA;
    float* nxt = bufB;

    for (int layer = 0; layer < 4; ++layer) {
        __syncthreads();
        const float4* wsrc = reinterpret_cast<const float4*>(fc_w + layer * 4096);
        for (int u = tid; u < 1024; u += 512) {
            const int oo = u >> 4, f = u & 15;
            *reinterpret_cast<float4*>(&w_lds[oo * 68 + f * 4]) = wsrc[u];
        }
        __syncthreads();
        const float bias = fc_b[layer * 64 + o];
        const float4* wr = reinterpret_cast<const float4*>(&w_lds[o * 68]);
        #pragma unroll
        for (int rb = 0; rb < 2; ++rb) {
            const int r = rr + rb * 8;
            float acc = bias;
            const float4* cr = reinterpret_cast<const float4*>(&cur[r * 68]);
            #pragma unroll
            for (int t = 0; t < 16; ++t) {
                const float4 c = cr[t], wv = wr[t];
                acc += c.x * wv.x + c.y * wv.y + c.z * wv.z + c.w * wv.w;
            }
            nxt[r * 68 + o] = fmaxf(acc, 0.f);
        }
        float* tmp = cur; cur = nxt; nxt = tmp;
    }
    __syncthreads();

    if (o < 3) {
        #pragma unroll
        for (int rb = 0; rb < 2; ++rb) {
            const int r = rr + rb * 8;
            float acc = bout[o];
            #pragma unroll
            for (int hh = 0; hh < 64; ++hh)
                acc += cur[r * 68 + hh] * wo_lds[o * 64 + hh];
            out[(R0 + r) * 3 + o] = acc;
        }
    }
}

// ---------------------------------------------------------------------------
extern "C" void kernel_launch(void* const* d_in, const int* in_sizes, int n_in,
                              void* d_out, int out_size, void* d_ws, size_t ws_size,
                              hipStream_t stream) {
    const float* x    = (const float*)d_in[0];
    const float* Wq   = (const float*)d_in[1];
    const float* bq   = (const float*)d_in[2];
    const float* Wk   = (const float*)d_in[3];
    const float* bk   = (const float*)d_in[4];
    const float* Wv   = (const float*)d_in[5];
    const float* bv   = (const float*)d_in[6];
    const float* PE   = (const float*)d_in[7];
    const float* fc_w = (const float*)d_in[8];
    const float* fc_b = (const float*)d_in[9];
    const float* Wout = (const float*)d_in[10];
    const float* bout = (const float*)d_in[11];
    float* out = (float*)d_out;

    float* ws = (float*)d_ws;
    float* qT   = ws;                      // 2,097,152 f
    float* kT   = qT + 2097152;            // 2,097,152 f
    float* vT   = kT + 2097152;            // 131,072 f
    float* attT = vT + 131072;             // 122,880 f  [n][h][960]
    unsigned short* XhG = (unsigned short*)(attT + 122880);
    unsigned short* XlG = XhG + 524288;
    unsigned short* WhG = XlG + 524288;
    unsigned short* WlG = WhG + 540672;

    convert_split<<<1040, 256, 0, stream>>>(x, Wq, Wk, Wv, XhG, XlG, WhG, WlG);
    qkv_mfma<<<544, 256, 0, stream>>>(XhG, XlG, WhG, WlG, bq, bk, bv, qT, kT, vT);
    attn_kernel<<<dim3(4, 64, 2), 256, 0, stream>>>(qT, kT, vT, PE, attT);
    fc_kernel<<<120, 512, 0, stream>>>(attT, fc_w, fc_b, Wout, bout, out);
}